// Round 15
// baseline (19897.981 us; speedup 1.0000x reference)
//
#include <hip/hip_runtime.h>
#include <math.h>

// Problem constants
constexpr int NB = 32, NT = 512, NH = 256, NE = 256, NS = 50, NV = 10000;
constexpr int SPAD = 264;   // padded stack row (f16 elems)

typedef _Float16 h2 __attribute__((ext_vector_type(2)));
typedef _Float16 h4 __attribute__((ext_vector_type(4)));
typedef _Float16 h8 __attribute__((ext_vector_type(8)));
typedef float f32x4 __attribute__((ext_vector_type(4)));

#define FMA4(acc, Wv, Xv) acc += (Wv).x*(Xv).x + (Wv).y*(Xv).y + (Wv).z*(Xv).z + (Wv).w*(Xv).w

#if __has_builtin(__builtin_amdgcn_fdot2)
__device__ __forceinline__ float dot2f(h2 a, h2 b, float c) { return __builtin_amdgcn_fdot2(a, b, c, false); }
#else
__device__ __forceinline__ float dot2f(h2 a, h2 b, float c) { return c + (float)a[0]*(float)b[0] + (float)a[1]*(float)b[1]; }
#endif
__device__ __forceinline__ float sigm(float x) { return 1.f / (1.f + __expf(-x)); }
__device__ __forceinline__ float tanh_f(float x) { const float e = __expf(2.f * x); return 1.f - 2.f / (e + 1.f); }

// ---- asm pipelined load primitives (r9 rules: consume-before-reissue, counted waits) ----
__device__ __forceinline__ void gload16(h8& d, const _Float16* p) {
  asm volatile("global_load_dwordx4 %0, %1, off" : "=&v"(d) : "v"(p));
}
#define VWAIT4() asm volatile("s_waitcnt vmcnt(4)" ::: "memory")
#define VWAIT0() asm volatile("s_waitcnt vmcnt(0)" ::: "memory")
#define SBAR()   __builtin_amdgcn_sched_barrier(0)

// ---- packed (MFMA-fragment-order) f16 arenas in d_ws; offsets in halves ----
// W0/W1 rows PERMUTED so quad q owns all 4 gates of cells [q*64, q*64+64):
//   packed row r -> original g*256 + q*64 + jcl, with q=r>>8, g=(r>>6)&3, jcl=r&63.
constexpr size_t P_W0  = 0;         // M=1024 K=512 (permuted rows)
constexpr size_t P_W1  = 524288;    // M=1024 K=512 (permuted rows)
constexpr size_t P_SW1 = 1048576;   // M=256  K=512
constexpr size_t P_SW2 = 1179648;   // M=256  K=256
constexpr size_t P_VWO = 1245184;   // M=256  K=256  val_w out part
constexpr size_t P_VWS = 1310720;   // M=256  K=256  val_w stack part
constexpr size_t P_GW  = 1376256;   // [512] linear
constexpr size_t H_TOTAL = 1376768;
constexpr size_t F_BC0 = H_TOTAL / 2;    // [1024] fp32 (ORIGINAL row order)
constexpr size_t F_BC1 = F_BC0 + 1024;   // [1024]
// exchange slots + counters/flags
constexpr size_t F_XB  = F_BC1 + 1024;   // [4][32][256]  B partial sums (K-split, isid only)
constexpr size_t F_XD  = F_XB + 32768;   // [4][32][1024] D h-slices (64 words used)
constexpr size_t F_XE  = F_XD + 131072;  // [4][32][1024] E h-slices
constexpr size_t F_CTR = F_XE + 131072;  // u32: [32][16] B ctrs, flags [2][32][4][16]

// ===================== prologue: fragment-pack weights (proven r13) =====================
__global__ __launch_bounds__(256) void prep_kernel(
    const float* wih0, const float* whh0, const float* bih0, const float* bhh0,
    const float* wih1, const float* whh1, const float* bih1, const float* bhh1,
    const float* stw1, const float* stw2, const float* valw, const float* gatew,
    float* ws) {
  _Float16* hw = (_Float16*)ws;
  const int gt = blockIdx.x * blockDim.x + threadIdx.x;
  const int np = gridDim.x * blockDim.x;

  auto pack = [&](size_t off, int M, int K, auto src) {
    const int KT = K / 32;
    for (int i = gt; i < M * K; i += np) {
      const int j = i & 7, l = (i >> 3) & 63, rem = i >> 9;
      const int kt = rem % KT, mt = rem / KT;
      const int row = mt * 16 + (l & 15), col = kt * 32 + (l >> 4) * 8 + j;
      hw[off + i] = (_Float16)src(row, col);
    }
  };
  auto lstm_perm = [](int r) {
    const int q = r >> 8, g = (r >> 6) & 3, jcl = r & 63;
    return g * 256 + q * 64 + jcl;
  };
  pack(P_W0, 1024, 512, [&](int r, int c) {
    const int o = lstm_perm(r);
    return c < 256 ? wih0[(size_t)o * 256 + c] : whh0[(size_t)o * 256 + c - 256];
  });
  pack(P_W1, 1024, 512, [&](int r, int c) {
    const int o = lstm_perm(r);
    return c < 256 ? wih1[(size_t)o * 256 + c] : whh1[(size_t)o * 256 + c - 256];
  });
  pack(P_SW1, 256, 512, [&](int r, int c) { return stw1[(size_t)r * 512 + c]; });
  pack(P_SW2, 256, 256, [&](int r, int c) { return stw2[(size_t)r * 256 + c]; });
  pack(P_VWO, 256, 256, [&](int r, int c) { return valw[(size_t)r * 512 + 256 + c]; });
  pack(P_VWS, 256, 256, [&](int r, int c) { return valw[(size_t)r * 512 + c]; });
  for (int i = gt; i < 512; i += np) hw[P_GW + i] = (_Float16)gatew[i];
  for (int i = gt; i < 1024; i += np) {
    ws[F_BC0 + i] = bih0[i] + bhh0[i];
    ws[F_BC1 + i] = bih1[i] + bhh1[i];
  }
}

// Full-K GEMV pipeline (proven). mtw = local output tile base.
template <int KT, int NMT>
__device__ __forceinline__ void gemv_pipe(const _Float16* __restrict__ wp, int mt0, int mtw,
                                          const _Float16* __restrict__ xA,
                                          const _Float16* __restrict__ xB,
                                          float* __restrict__ pre, int l) {
  const int lr = l & 15, lk = l >> 4;
  constexpr int TOT = KT * NMT;
  constexpr int NC  = TOT / 4;
  const _Float16* base = wp + ((size_t)mt0 * KT * 64 + (size_t)l) * 8;
  h8 A[4], B[4];
  #pragma unroll
  for (int i = 0; i < 4; ++i) gload16(A[i], base + (size_t)i * 512);
  if constexpr (NC > 1) {
    #pragma unroll
    for (int i = 0; i < 4; ++i) gload16(B[i], base + (size_t)(4 + i) * 512);
  }
  f32x4 c = {0.f, 0.f, 0.f, 0.f};
  #pragma unroll
  for (int ch = 0; ch < NC; ++ch) {
    h8* cur = (ch & 1) ? B : A;
    if (ch < NC - 1) VWAIT4(); else VWAIT0();
    SBAR();
    #pragma unroll
    for (int i = 0; i < 4; ++i) {
      const int f = ch * 4 + i;
      const int kt = f % KT;
      const _Float16* xb = (KT > 8) ? ((kt < 8) ? xA + kt * 32 : xB + (kt - 8) * 32)
                                    : (xA + kt * 32);
      const h8 x = *(const h8*)(xb + lk * 8);
      c = __builtin_amdgcn_mfma_f32_16x16x32_f16(cur[i], x, c, 0, 0, 0);
      if (kt == KT - 1) {
        if (lr == 0) *((f32x4*)&pre[(mtw + f / KT) * 16 + lk * 4]) = c;
        c = (f32x4){0.f, 0.f, 0.f, 0.f};
      }
    }
    if (ch + 2 < NC) {
      #pragma unroll
      for (int i = 0; i < 4; ++i) gload16(cur[i], base + (size_t)((ch + 2) * 4 + i) * 512);
    }
  }
}

// Partial-K GEMV (B phase only; proven)
template <int KT, int NMT, int KTC>
__device__ __forceinline__ void gemv_part(const _Float16* __restrict__ wp, int mt0, int kt0,
                                          const _Float16* __restrict__ xA,
                                          const _Float16* __restrict__ xB,
                                          float* __restrict__ pre, int l) {
  const int lr = l & 15, lk = l >> 4;
  constexpr int TOT = NMT * KTC;
  constexpr int NC  = TOT / 4;
  h8 A[4], B[4];
  auto addr = [&](int f) {
    const int mt = mt0 + f / KTC, kt = kt0 + f % KTC;
    return wp + ((size_t)(mt * KT + kt) * 64 + (size_t)l) * 8;
  };
  #pragma unroll
  for (int i = 0; i < 4; ++i) gload16(A[i], addr(i));
  if constexpr (NC > 1) {
    #pragma unroll
    for (int i = 0; i < 4; ++i) gload16(B[i], addr(4 + i));
  }
  f32x4 c = {0.f, 0.f, 0.f, 0.f};
  #pragma unroll
  for (int ch = 0; ch < NC; ++ch) {
    h8* cur = (ch & 1) ? B : A;
    if (ch < NC - 1) VWAIT4(); else VWAIT0();
    SBAR();
    #pragma unroll
    for (int i = 0; i < 4; ++i) {
      const int f = ch * 4 + i, ktl = f % KTC, kt = kt0 + ktl;
      const _Float16* xb = (KT > 8) ? ((kt < 8) ? xA + kt * 32 : xB + (kt - 8) * 32)
                                    : (xA + kt * 32);
      const h8 x = *(const h8*)(xb + lk * 8);
      c = __builtin_amdgcn_mfma_f32_16x16x32_f16(cur[i], x, c, 0, 0, 0);
      if (ktl == KTC - 1) {
        if (lr == 0) *((f32x4*)&pre[(mt0 + f / KTC) * 16 + lk * 4]) = c;
        c = (f32x4){0.f, 0.f, 0.f, 0.f};
      }
    }
    if (ch + 2 < NC) {
      #pragma unroll
      for (int i = 0; i < 4; ++i) gload16(cur[i], addr((ch + 2) * 4 + i));
    }
  }
}

// Quad partial-sum exchange for B (proven; counter-based, isid only)
__device__ __forceinline__ void xchg(float* base, unsigned* ctr, unsigned target,
                                     int q, int b, int n, float* s_pre, int tid) {
  unsigned* mine = (unsigned*)(base + ((size_t)q * NB + b) * n);
  for (int i = tid; i < n; i += 1024)
    __hip_atomic_store(mine + i, __float_as_uint(s_pre[i]), __ATOMIC_RELAXED, __HIP_MEMORY_SCOPE_AGENT);
  __syncthreads();
  if (tid == 0) {
    asm volatile("s_waitcnt vmcnt(0)" ::: "memory");
    __hip_atomic_fetch_add(ctr, 1u, __ATOMIC_RELAXED, __HIP_MEMORY_SCOPE_AGENT);
    while (__hip_atomic_load(ctr, __ATOMIC_RELAXED, __HIP_MEMORY_SCOPE_AGENT) < target)
      __builtin_amdgcn_s_sleep(1);
  }
  __syncthreads();
  for (int i = tid; i < n; i += 1024) {
    float s = 0.f;
    #pragma unroll
    for (int p = 0; p < 4; ++p) {
      unsigned* sp = (unsigned*)(base + ((size_t)p * NB + b) * n);
      s += __uint_as_float(__hip_atomic_load(sp + i, __ATOMIC_RELAXED, __HIP_MEMORY_SCOPE_AGENT));
    }
    s_pre[i] = s;
  }
  __syncthreads();
}

// ====== recurrent scan: QUAD/WG per row (128 WGs), rendezvous hidden under prefetch ======
__global__ __launch_bounds__(1024, 4) void rnn14_kernel(
    const int* __restrict__ tokens, const int* __restrict__ scope_idx,
    const int* __restrict__ is_id, const int* __restrict__ umask,
    const int* __restrict__ lengths, const float* __restrict__ emb,
    const float* __restrict__ stb1, const float* __restrict__ stb2,
    const float* __restrict__ gateb, const float* __restrict__ valb,
    const float* __restrict__ h0, const float* __restrict__ c0,
    float* __restrict__ ws, float* __restrict__ out) {
  const int bid = blockIdx.x, tid = threadIdx.x;
  const int b = bid >> 2, q = bid & 3;   // XCD-aligned quad mapping (proven r12)
  const int len = lengths[b];
  const _Float16* hw = (const _Float16*)ws;
  const int w = tid >> 6, l = tid & 63;
  float* xb_slot = ws + F_XB;
  unsigned* xd = (unsigned*)(ws + F_XD);
  unsigned* xe = (unsigned*)(ws + F_XE);
  unsigned* ctrb  = (unsigned*)(ws + F_CTR) + b * 16;
  unsigned* flags = (unsigned*)(ws + F_CTR) + 512;   // [2][32][4][16]
  unsigned* flagD = flags + ((0 * NB + b) * 4 + q) * 16;
  unsigned* flagE = flags + ((1 * NB + b) * 4 + q) * 16;

  __shared__ __align__(16) _Float16 s_stkh[64][SPAD];
  __shared__ __align__(16) float    s_stk32[NS][NH];
  __shared__ __align__(16) float    s_pre[1024];
  __shared__ __align__(16) float    s_hf[256];
  __shared__ __align__(16) float    s_c[2][NH];
  __shared__ __align__(16) _Float16 s_h0h[2][NH], s_h1h[2][NH];
  __shared__ __align__(16) _Float16 s_embh[NH], s_z[NH], s_xin[NH];
  __shared__ __align__(16) float    s_vb[NH], s_b1[NH], s_b2[NH];
  __shared__ __align__(16) float    s_bc0[1024], s_bc1[1024];
  __shared__ __align__(16) _Float16 s_gw[512];
  __shared__ float s_gp[NS];       // gate stack-partials (computed in D-rendezvous window)
  __shared__ float s_gate[NS];
  __shared__ int   s_um[NS];
  __shared__ float s_gb;

  // ---- one-time init (replicated)
  for (int i = tid; i < 64 * SPAD; i += 1024) ((_Float16*)s_stkh)[i] = (_Float16)0.f;
  for (int i = tid; i < NS * NH; i += 1024) ((float*)s_stk32)[i] = 0.f;
  s_bc0[tid] = ws[F_BC0 + tid];
  s_bc1[tid] = ws[F_BC1 + tid];
  if (tid < NH) {
    s_h0h[0][tid] = (_Float16)h0[b * NH + tid];
    s_h1h[0][tid] = (_Float16)h0[NB * NH + b * NH + tid];
    s_c[0][tid] = c0[b * NH + tid];
    s_c[1][tid] = c0[NB * NH + b * NH + tid];
    s_vb[tid] = valb[tid]; s_b1[tid] = stb1[tid]; s_b2[tid] = stb2[tid];
  }
  if (tid < 64) ((h8*)s_gw)[tid] = ((const h8*)(hw + P_GW))[tid];
  if (tid == 0) s_gb = gateb[0];
  __syncthreads();

  unsigned epB = 0;

  for (int t = 0; t < len; ++t) {
    const int p0 = t & 1, p1 = p0 ^ 1;
    const int tok  = tokens[b * NT + t];
    const int sx   = scope_idx[b * NT + t];
    const int isid = is_id[b * NT + t];
    const unsigned stamp = (unsigned)(t + 1);
    const int lr = l & 15, lk = l >> 4;
    const _Float16* baseE = hw + P_W1 + ((size_t)(q * 16 + w) * 16 * 64 + (size_t)l) * 8;
    const _Float16* baseV = hw + P_VWO + ((size_t)(w * 2) * 8 * 64 + (size_t)l) * 8;

    // ---- A: emb -> LDS f16, umask (replicated)
    if (tid < 64) {
      const float4 e = ((const float4*)(emb + (size_t)tok * NE))[tid];
      h4 v = { (_Float16)e.x, (_Float16)e.y, (_Float16)e.z, (_Float16)e.w };
      ((h4*)s_embh)[tid] = v;
    } else if (tid >= 64 && tid < 64 + NS) {
      s_um[tid - 64] = umask[((size_t)b * NT + t) * NS + (tid - 64)];
    }
    __syncthreads();

    if (isid) {
      // ---- B (K-split, proven): partial z over kt [q*4, q*4+4)
      gemv_part<16, 1, 4>(hw + P_SW1, w, q * 4, &s_stkh[sx][0], s_embh, s_pre, l);
      __syncthreads();
      ++epB;
      xchg(xb_slot, ctrb, 4u * epB, q, b, 256, s_pre, tid);
      if (tid < 256) s_z[tid] = (_Float16)fmaxf(s_pre[tid] + s_b1[tid], 0.f);
      __syncthreads();
      // ---- C: full (replicated)
      gemv_pipe<8, 1>(hw + P_SW2, w, w, s_z, s_z, s_pre, l);
      __syncthreads();
      if (tid < 256) s_xin[tid] = (_Float16)(s_pre[tid] + s_b2[tid]);
      __syncthreads();
    } else {
      if (tid < 32) ((h8*)s_xin)[tid] = ((const h8*)s_embh)[tid];
      __syncthreads();
    }

    // ---- D (M-split): full-K pre-acts for quad's 256 permuted rows
    gemv_pipe<16, 1>(hw + P_W0, q * 16 + w, w, s_xin, s_h0h[p0], s_pre, l);
    __syncthreads();
    if (tid < 64) {   // owner nonlinearity: cells q*64 + jcl (wave 0)
      const int jcl = tid, cell = q * 64 + jcl;
      const float iv = s_pre[jcl]       + s_bc0[cell];
      const float fv = s_pre[64 + jcl]  + s_bc0[256 + cell];
      const float gv = s_pre[128 + jcl] + s_bc0[512 + cell];
      const float ov = s_pre[192 + jcl] + s_bc0[768 + cell];
      const float c_ = sigm(fv) * s_c[0][cell] + sigm(iv) * tanh_f(gv);
      s_c[0][cell] = c_;
      const float h_ = sigm(ov) * tanh_f(c_);
      __hip_atomic_store(xd + ((size_t)q * NB + b) * 1024 + jcl, __float_as_uint(h_),
                         __ATOMIC_RELAXED, __HIP_MEMORY_SCOPE_AGENT);
      VWAIT0();                                        // drain publish before flag
    }
    if (tid == 0)
      __hip_atomic_store(flagD, stamp, __ATOMIC_RELAXED, __HIP_MEMORY_SCOPE_AGENT);
    // ==== D-rendezvous window: E weight prefetch + gate stack-partials overlap the spin
    h8 EA[4], EB[4];
    #pragma unroll
    for (int i = 0; i < 4; ++i) gload16(EA[i], baseE + (size_t)i * 512);
    #pragma unroll
    for (int i = 0; i < 4; ++i) gload16(EB[i], baseE + (size_t)(4 + i) * 512);
    if (w >= 8) {     // gate stack-partials from LDS (stack is stable until F4)
      const int wp = w - 8;
      const h2* gs = (const h2*)s_gw;
      for (int j = 0; j < 7; ++j) {
        const int s = wp + 8 * j;
        if (s < NS) {
          const h2* sr = (const h2*)s_stkh[s];
          float p = dot2f(gs[2 * l], sr[2 * l], 0.f);
          p = dot2f(gs[2 * l + 1], sr[2 * l + 1], p);
          #pragma unroll
          for (int m = 1; m < 64; m <<= 1) p += __shfl_xor(p, m, 64);
          if (l == 0) s_gp[s] = p;
        }
      }
    }
    if (tid < 4) {
      unsigned* f = flags + ((0 * NB + b) * 4 + tid) * 16;
      while (__hip_atomic_load(f, __ATOMIC_RELAXED, __HIP_MEMORY_SCOPE_AGENT) < stamp)
        __builtin_amdgcn_s_sleep(1);
    }
    __syncthreads();
    if (tid < 256) {   // gather h0 (identical conversion in all replicas)
      const unsigned v = __hip_atomic_load(xd + ((size_t)(tid >> 6) * NB + b) * 1024 + (tid & 63),
                                           __ATOMIC_RELAXED, __HIP_MEMORY_SCOPE_AGENT);
      s_h0h[p1][tid] = (_Float16)__uint_as_float(v);
    }
    __syncthreads();

    // ---- E consume (prologue already in EA/EB): full-K pre-acts on W1
    {
      f32x4 c = {0.f, 0.f, 0.f, 0.f};
      #pragma unroll
      for (int ch = 0; ch < 4; ++ch) {
        h8* cur = (ch & 1) ? EB : EA;
        if (ch < 3) VWAIT4(); else VWAIT0();
        SBAR();
        #pragma unroll
        for (int i = 0; i < 4; ++i) {
          const int kt = ch * 4 + i;
          const _Float16* xb = (kt < 8) ? (const _Float16*)s_h0h[p1] + kt * 32
                                        : (const _Float16*)s_h1h[p0] + (kt - 8) * 32;
          c = __builtin_amdgcn_mfma_f32_16x16x32_f16(cur[i], *(const h8*)(xb + lk * 8), c, 0, 0, 0);
        }
        if (ch + 2 < 4) {
          #pragma unroll
          for (int i = 0; i < 4; ++i) gload16(cur[i], baseE + (size_t)((ch + 2) * 4 + i) * 512);
        }
      }
      if (lr == 0) *((f32x4*)&s_pre[w * 16 + lk * 4]) = c;
    }
    __syncthreads();
    if (tid < 64) {
      const int jcl = tid, cell = q * 64 + jcl;
      const float iv = s_pre[jcl]       + s_bc1[cell];
      const float fv = s_pre[64 + jcl]  + s_bc1[256 + cell];
      const float gv = s_pre[128 + jcl] + s_bc1[512 + cell];
      const float ov = s_pre[192 + jcl] + s_bc1[768 + cell];
      const float c_ = sigm(fv) * s_c[1][cell] + sigm(iv) * tanh_f(gv);
      s_c[1][cell] = c_;
      const float h_ = sigm(ov) * tanh_f(c_);
      __hip_atomic_store(xe + ((size_t)q * NB + b) * 1024 + jcl, __float_as_uint(h_),
                         __ATOMIC_RELAXED, __HIP_MEMORY_SCOPE_AGENT);
      VWAIT0();
    }
    if (tid == 0)
      __hip_atomic_store(flagE, stamp, __ATOMIC_RELAXED, __HIP_MEMORY_SCOPE_AGENT);
    // ==== E-rendezvous window: vproj weight prefetch (waves 0-7) overlaps the spin
    h8 VA[4], VB[4];
    if (w < 8) {
      #pragma unroll
      for (int i = 0; i < 4; ++i) gload16(VA[i], baseV + (size_t)i * 512);
      #pragma unroll
      for (int i = 0; i < 4; ++i) gload16(VB[i], baseV + (size_t)(4 + i) * 512);
    }
    if (tid < 4) {
      unsigned* f = flags + ((1 * NB + b) * 4 + tid) * 16;
      while (__hip_atomic_load(f, __ATOMIC_RELAXED, __HIP_MEMORY_SCOPE_AGENT) < stamp)
        __builtin_amdgcn_s_sleep(1);
    }
    __syncthreads();
    if (tid < 256) {
      const unsigned v = __hip_atomic_load(xe + ((size_t)(tid >> 6) * NB + b) * 1024 + (tid & 63),
                                           __ATOMIC_RELAXED, __HIP_MEMORY_SCOPE_AGENT);
      const float h_ = __uint_as_float(v);
      s_hf[tid] = h_;
      s_h1h[p1][tid] = (_Float16)h_;
    }
    __syncthreads();
    if (q == 0 && tid < 64)   // feats (f32, one writer)
      ((float4*)(out + ((size_t)b * NT + t) * NV))[tid] = ((const float4*)s_hf)[tid];

    // ---- F: vproj consume (waves 0-7, prologue in VA/VB) + gate finish (waves 8-15)
    if (w < 8) {
      f32x4 c = {0.f, 0.f, 0.f, 0.f};
      #pragma unroll
      for (int ch = 0; ch < 4; ++ch) {
        h8* cur = (ch & 1) ? VB : VA;
        if (ch < 3) VWAIT4(); else VWAIT0();
        SBAR();
        #pragma unroll
        for (int i = 0; i < 4; ++i) {
          const int f = ch * 4 + i, kt = f & 7;
          const h8 x = *(const h8*)((const _Float16*)s_h1h[p1] + kt * 32 + lk * 8);
          c = __builtin_amdgcn_mfma_f32_16x16x32_f16(cur[i], x, c, 0, 0, 0);
          if (kt == 7) {
            if (lr == 0) *((f32x4*)&s_pre[(w * 2 + f / 8) * 16 + lk * 4]) = c;
            c = (f32x4){0.f, 0.f, 0.f, 0.f};
          }
        }
        if (ch + 2 < 4) {
          #pragma unroll
          for (int i = 0; i < 4; ++i) gload16(cur[i], baseV + (size_t)((ch + 2) * 4 + i) * 512);
        }
      }
    } else {
      const int wp = w - 8;
      const h2* go = (const h2*)(s_gw + 256);
      const h2* oh = (const h2*)s_h1h[p1];
      float po = dot2f(go[2 * l], oh[2 * l], 0.f);
      po = dot2f(go[2 * l + 1], oh[2 * l + 1], po);
      #pragma unroll
      for (int m = 1; m < 64; m <<= 1) po += __shfl_xor(po, m, 64);
      if (l == 0) {
        for (int j = 0; j < 7; ++j) {
          const int s = wp + 8 * j;
          if (s < NS) s_gate[s] = (s_um[s] > 0) ? -1.f : sigm(s_gp[s] + po + s_gb);
        }
      }
    }
    __syncthreads();

    // ---- F4: stack GEMM, de-duplicated (proven r13; wave w -> mt=w)
    {
      const int r = w * 16 + lr;
      const _Float16* baseB = hw + P_VWS + ((size_t)(w * 8) * 64 + (size_t)l) * 8;
      h8 bf0[4], bf1[4];
      #pragma unroll
      for (int i = 0; i < 4; ++i) gload16(bf0[i], baseB + (size_t)i * 512);
      #pragma unroll
      for (int i = 0; i < 4; ++i) gload16(bf1[i], baseB + (size_t)(4 + i) * 512);
      const float vpr = s_pre[r] + s_vb[r];
      float nsv[4][4];
      #pragma unroll
      for (int st = 0; st < 4; ++st) {
        h8 af[8];
        #pragma unroll
        for (int kt = 0; kt < 8; ++kt)
          af[kt] = *(const h8*)&s_stkh[st * 16 + lr][kt * 32 + lk * 8];
        if (st == 0) { VWAIT4(); SBAR(); }
        f32x4 c = {0.f, 0.f, 0.f, 0.f};
        #pragma unroll
        for (int kt = 0; kt < 4; ++kt)
          c = __builtin_amdgcn_mfma_f32_16x16x32_f16(af[kt], bf0[kt], c, 0, 0, 0);
        if (st == 0) { VWAIT0(); SBAR(); }
        #pragma unroll
        for (int kt = 4; kt < 8; ++kt)
          c = __builtin_amdgcn_mfma_f32_16x16x32_f16(af[kt], bf1[kt - 4], c, 0, 0, 0);
        #pragma unroll
        for (int i = 0; i < 4; ++i) {
          const int s = st * 16 + lk * 4 + i;
          float ns = 0.f;
          if (s < NS) {
            const float gv = s_gate[s];
            if (gv >= 0.f) ns = s_stk32[s][r] * (1.f - gv) + gv * tanh_f(c[i] + vpr);
          }
          nsv[st][i] = ns;
        }
      }
      __syncthreads();   // all reads of stack/gates complete before any write
      #pragma unroll
      for (int st = 0; st < 4; ++st) {
        #pragma unroll
        for (int i = 0; i < 4; ++i) {
          const int s = st * 16 + lk * 4 + i;
          if (s < NS) { s_stk32[s][r] = nsv[st][i]; s_stkh[s][r] = (_Float16)nsv[st][i]; }
        }
      }
    }
    __syncthreads();
  }
}

// ===================== logits epilogue (feats live in out[b][t][0:256]) =====================
constexpr int TBR = 32;
__global__ __launch_bounds__(256) void logits_kernel(
    const float* __restrict__ w1, const float* __restrict__ b1,
    const float* __restrict__ w2, const float* __restrict__ b2,
    const int* __restrict__ lengths, float* __restrict__ out) {
  const int blk = blockIdx.x;
  const int b = blk >> 4;
  const int t0 = (blk & 15) * TBR;
  const int tid = threadIdx.x;
  const int len = lengths[b];
  __shared__ __align__(16) float s_fe[TBR][NH];
  __shared__ __align__(16) float s_hid[TBR][NH];

  for (int r = 0; r < TBR; ++r) {
    const int t = t0 + r;
    s_fe[r][tid] = (t < len) ? out[((size_t)b * NT + t) * NV + tid] : 0.f;
  }
  __syncthreads();
  for (int r = 0; r < TBR; ++r) {
    float acc = b1[tid];
    const float4* fr = (const float4*)s_fe[r];
    const float4* wr = (const float4*)(w1 + (size_t)tid * NH);
    #pragma unroll 8
    for (int k = 0; k < NH / 4; ++k) { float4 wv = wr[k]; float4 fv = fr[k]; FMA4(acc, wv, fv); }
    s_hid[r][tid] = fmaxf(acc, 0.f);
  }
  __syncthreads();
  for (int r = 0; r < TBR; ++r) {
    const int t = t0 + r;
    if (t >= len) {
      float4* orow = (float4*)(out + ((size_t)b * NT + t) * NV);
      const float4 m1 = make_float4(-1.f, -1.f, -1.f, -1.f);
      for (int i = tid; i < NV / 4; i += 256) orow[i] = m1;
    }
  }
  if (t0 >= len) return;
  for (int pass = 0; pass < (NV + 511) / 512; ++pass) {
    const int v0 = pass * 512 + tid * 2;
    if (v0 >= NV) continue;
    float acc0[TBR], acc1[TBR];
    #pragma unroll
    for (int r = 0; r < TBR; ++r) { acc0[r] = 0.f; acc1[r] = 0.f; }
    const float4* wa = (const float4*)(w2 + (size_t)v0 * NH);
    const float4* wb = (const float4*)(w2 + (size_t)(v0 + 1) * NH);
    for (int k = 0; k < NH / 4; ++k) {
      const float4 w0 = wa[k], w1v = wb[k];
      #pragma unroll
      for (int r = 0; r < TBR; ++r) {
        const float4 hx = *(const float4*)&s_hid[r][k * 4];
        acc0[r] += w0.x * hx.x + w0.y * hx.y + w0.z * hx.z + w0.w * hx.w;
        acc1[r] += w1v.x * hx.x + w1v.y * hx.y + w1v.z * hx.z + w1v.w * hx.w;
      }
    }
    const float bb0 = b2[v0], bb1 = b2[v0 + 1];
    for (int r = 0; r < TBR; ++r) {
      const int t = t0 + r;
      if (t < len) {
        float2 st = make_float2(acc0[r] + bb0, acc1[r] + bb1);
        *(float2*)(out + ((size_t)b * NT + t) * NV + v0) = st;
      }
    }
  }
}

extern "C" void kernel_launch(void* const* d_in, const int* in_sizes, int n_in,
                              void* d_out, int out_size, void* d_ws, size_t ws_size,
                              hipStream_t stream) {
  (void)in_sizes; (void)n_in; (void)out_size; (void)ws_size;
  const int* tokens    = (const int*)d_in[0];
  const int* scope_idx = (const int*)d_in[1];
  const int* is_id     = (const int*)d_in[2];
  const int* umask     = (const int*)d_in[3];
  const int* lengths   = (const int*)d_in[4];
  const float* emb   = (const float*)d_in[5];
  const float* wih0  = (const float*)d_in[6];  const float* whh0 = (const float*)d_in[7];
  const float* bih0  = (const float*)d_in[8];  const float* bhh0 = (const float*)d_in[9];
  const float* wih1  = (const float*)d_in[10]; const float* whh1 = (const float*)d_in[11];
  const float* bih1  = (const float*)d_in[12]; const float* bhh1 = (const float*)d_in[13];
  const float* stw1  = (const float*)d_in[14]; const float* stb1 = (const float*)d_in[15];
  const float* stw2  = (const float*)d_in[16]; const float* stb2 = (const float*)d_in[17];
  const float* gatew = (const float*)d_in[18]; const float* gateb = (const float*)d_in[19];
  const float* valw  = (const float*)d_in[20]; const float* valb  = (const float*)d_in[21];
  const float* outw1 = (const float*)d_in[22]; const float* outb1 = (const float*)d_in[23];
  const float* outw2 = (const float*)d_in[24]; const float* outb2 = (const float*)d_in[25];
  const float* h0 = (const float*)d_in[26];
  const float* c0 = (const float*)d_in[27];
  float* ws = (float*)d_ws;
  float* out = (float*)d_out;

  // reset B counters + D/E flags (each launch; graph replay includes this)
  (void)hipMemsetAsync(ws + F_CTR, 0, (512 + 2 * 32 * 4 * 16) * 4, stream);

  prep_kernel<<<dim3(256), dim3(256), 0, stream>>>(
      wih0, whh0, bih0, bhh0, wih1, whh1, bih1, bhh1, stw1, stw2, valw, gatew, ws);

  rnn14_kernel<<<dim3(128), dim3(1024), 0, stream>>>(
      tokens, scope_idx, is_id, umask, lengths, emb,
      stb1, stb2, gateb, valb, h0, c0, ws, out);

  logits_kernel<<<dim3(NB * 16), dim3(256), 0, stream>>>(
      outw1, outb1, outw2, outb2, lengths, out);
}

// Round 16
// 15083.995 us; speedup vs baseline: 1.3191x; 1.3191x over previous
//
#include <hip/hip_runtime.h>
#include <math.h>

// Problem constants
constexpr int NB = 32, NT = 512, NH = 256, NE = 256, NS = 50, NV = 10000;
constexpr int SPAD = 264;   // padded stack row (f16 elems)
constexpr int TBR = 32;     // logits t-tile

typedef _Float16 h2 __attribute__((ext_vector_type(2)));
typedef _Float16 h4 __attribute__((ext_vector_type(4)));
typedef _Float16 h8 __attribute__((ext_vector_type(8)));
typedef float f32x4 __attribute__((ext_vector_type(4)));

#if __has_builtin(__builtin_amdgcn_fdot2)
__device__ __forceinline__ float dot2f(h2 a, h2 b, float c) { return __builtin_amdgcn_fdot2(a, b, c, false); }
#else
__device__ __forceinline__ float dot2f(h2 a, h2 b, float c) { return c + (float)a[0]*(float)b[0] + (float)a[1]*(float)b[1]; }
#endif
__device__ __forceinline__ float sigm(float x) { return 1.f / (1.f + __expf(-x)); }
__device__ __forceinline__ float tanh_f(float x) { const float e = __expf(2.f * x); return 1.f - 2.f / (e + 1.f); }

// ---- asm pipelined load primitives (r9 rules: consume-before-reissue, counted waits) ----
__device__ __forceinline__ void gload16(h8& d, const _Float16* p) {
  asm volatile("global_load_dwordx4 %0, %1, off" : "=&v"(d) : "v"(p));
}
#define VWAIT4() asm volatile("s_waitcnt vmcnt(4)" ::: "memory")
#define VWAIT0() asm volatile("s_waitcnt vmcnt(0)" ::: "memory")
#define SBAR()   __builtin_amdgcn_sched_barrier(0)

// ---- packed (MFMA-fragment-order) f16 arenas in d_ws; offsets in halves ----
// W0/W1 rows PERMUTED so quad q owns all 4 gates of cells [q*64, q*64+64):
//   packed row r -> original g*256 + q*64 + jcl, with q=r>>8, g=(r>>6)&3, jcl=r&63.
constexpr size_t P_W0  = 0;         // M=1024 K=512 (permuted rows)
constexpr size_t P_W1  = 524288;    // M=1024 K=512 (permuted rows)
constexpr size_t P_SW1 = 1048576;   // M=256  K=512
constexpr size_t P_SW2 = 1179648;   // M=256  K=256
constexpr size_t P_VWO = 1245184;   // M=256  K=256  val_w out part
constexpr size_t P_VWS = 1310720;   // M=256  K=256  val_w stack part
constexpr size_t P_GW  = 1376256;   // [512] linear
constexpr size_t P_LW1 = 1376768;   // M=256  K=256  out_w1 (logits stage 1)
constexpr size_t P_LW2 = 1442304;   // M=10000 K=256 out_w2 (625 m-tiles)
constexpr size_t H_TOTAL = 4002304;
constexpr size_t F_BC0 = H_TOTAL / 2;    // [1024] fp32 (ORIGINAL row order)
constexpr size_t F_BC1 = F_BC0 + 1024;   // [1024]
constexpr size_t F_XB  = F_BC1 + 1024;   // [4][32][256]  B z-slices (64 words used)
constexpr size_t F_XD  = F_XB + 32768;   // [4][32][1024] D h-slices (64 words used)
constexpr size_t F_XE  = F_XD + 131072;  // [4][32][1024] E h-slices
constexpr size_t F_CTR = F_XE + 131072;  // u32 flags [3][32][4][16]  (D=0,E=1,B=2)
constexpr size_t H_FEATS = 4608512;      // halves: [32][512][256] published feats (f16)

// ===================== prologue: fragment-pack weights =====================
__global__ __launch_bounds__(256) void prep_kernel(
    const float* wih0, const float* whh0, const float* bih0, const float* bhh0,
    const float* wih1, const float* whh1, const float* bih1, const float* bhh1,
    const float* stw1, const float* stw2, const float* valw, const float* gatew,
    const float* outw1, const float* outw2, float* ws) {
  _Float16* hw = (_Float16*)ws;
  const int gt = blockIdx.x * blockDim.x + threadIdx.x;
  const int np = gridDim.x * blockDim.x;

  auto pack = [&](size_t off, int M, int K, auto src) {
    const int KT = K / 32;
    for (int i = gt; i < M * K; i += np) {
      const int j = i & 7, l = (i >> 3) & 63, rem = i >> 9;
      const int kt = rem % KT, mt = rem / KT;
      const int row = mt * 16 + (l & 15), col = kt * 32 + (l >> 4) * 8 + j;
      hw[off + i] = (_Float16)src(row, col);
    }
  };
  auto lstm_perm = [](int r) {
    const int q = r >> 8, g = (r >> 6) & 3, jcl = r & 63;
    return g * 256 + q * 64 + jcl;
  };
  pack(P_W0, 1024, 512, [&](int r, int c) {
    const int o = lstm_perm(r);
    return c < 256 ? wih0[(size_t)o * 256 + c] : whh0[(size_t)o * 256 + c - 256];
  });
  pack(P_W1, 1024, 512, [&](int r, int c) {
    const int o = lstm_perm(r);
    return c < 256 ? wih1[(size_t)o * 256 + c] : whh1[(size_t)o * 256 + c - 256];
  });
  pack(P_SW1, 256, 512, [&](int r, int c) { return stw1[(size_t)r * 512 + c]; });
  pack(P_SW2, 256, 256, [&](int r, int c) { return stw2[(size_t)r * 256 + c]; });
  pack(P_VWO, 256, 256, [&](int r, int c) { return valw[(size_t)r * 512 + 256 + c]; });
  pack(P_VWS, 256, 256, [&](int r, int c) { return valw[(size_t)r * 512 + c]; });
  pack(P_LW1, 256, 256, [&](int r, int c) { return outw1[(size_t)r * 256 + c]; });
  pack(P_LW2, 10000, 256, [&](int r, int c) { return outw2[(size_t)r * 256 + c]; });
  for (int i = gt; i < 512; i += np) hw[P_GW + i] = (_Float16)gatew[i];
  for (int i = gt; i < 1024; i += np) {
    ws[F_BC0 + i] = bih0[i] + bhh0[i];
    ws[F_BC1 + i] = bih1[i] + bhh1[i];
  }
}

// Full-K GEMV pipeline (proven r13). mtw = local output tile base.
template <int KT, int NMT>
__device__ __forceinline__ void gemv_pipe(const _Float16* __restrict__ wp, int mt0, int mtw,
                                          const _Float16* __restrict__ xA,
                                          const _Float16* __restrict__ xB,
                                          float* __restrict__ pre, int l) {
  const int lr = l & 15, lk = l >> 4;
  constexpr int TOT = KT * NMT;
  constexpr int NC  = TOT / 4;
  const _Float16* base = wp + ((size_t)mt0 * KT * 64 + (size_t)l) * 8;
  h8 A[4], B[4];
  #pragma unroll
  for (int i = 0; i < 4; ++i) gload16(A[i], base + (size_t)i * 512);
  if constexpr (NC > 1) {
    #pragma unroll
    for (int i = 0; i < 4; ++i) gload16(B[i], base + (size_t)(4 + i) * 512);
  }
  f32x4 c = {0.f, 0.f, 0.f, 0.f};
  #pragma unroll
  for (int ch = 0; ch < NC; ++ch) {
    h8* cur = (ch & 1) ? B : A;
    if (ch < NC - 1) VWAIT4(); else VWAIT0();
    SBAR();
    #pragma unroll
    for (int i = 0; i < 4; ++i) {
      const int f = ch * 4 + i;
      const int kt = f % KT;
      const _Float16* xb = (KT > 8) ? ((kt < 8) ? xA + kt * 32 : xB + (kt - 8) * 32)
                                    : (xA + kt * 32);
      const h8 x = *(const h8*)(xb + lk * 8);
      c = __builtin_amdgcn_mfma_f32_16x16x32_f16(cur[i], x, c, 0, 0, 0);
      if (kt == KT - 1) {
        if (lr == 0) *((f32x4*)&pre[(mtw + f / KT) * 16 + lk * 4]) = c;
        c = (f32x4){0.f, 0.f, 0.f, 0.f};
      }
    }
    if (ch + 2 < NC) {
      #pragma unroll
      for (int i = 0; i < 4; ++i) gload16(cur[i], base + (size_t)((ch + 2) * 4 + i) * 512);
    }
  }
}

// ============== fused kernel: 128 scan WGs (quad M-split, r13) + 128 logits workers ======
__global__ __launch_bounds__(1024, 4) void rnn15_kernel(
    const int* __restrict__ tokens, const int* __restrict__ scope_idx,
    const int* __restrict__ is_id, const int* __restrict__ umask,
    const int* __restrict__ lengths, const float* __restrict__ emb,
    const float* __restrict__ stb1, const float* __restrict__ stb2,
    const float* __restrict__ gateb, const float* __restrict__ valb,
    const float* __restrict__ outb1, const float* __restrict__ outb2,
    const float* __restrict__ h0, const float* __restrict__ c0,
    float* __restrict__ ws, float* __restrict__ out) {
  const int wid = blockIdx.x, tid = threadIdx.x;
  const _Float16* hw = (const _Float16*)ws;
  const int w = tid >> 6, l = tid & 63;
  const int lr = l & 15, lk = l >> 4;
  unsigned* flags = (unsigned*)(ws + F_CTR);   // [3][32][4][16]

  __shared__ __align__(16) _Float16 s_stkh[64][SPAD];
  __shared__ __align__(16) float    s_stk32[NS][NH];
  __shared__ __align__(16) float    s_pre[1024];
  __shared__ __align__(16) float    s_hf[256];
  __shared__ __align__(16) float    s_c[2][NH];
  __shared__ __align__(16) _Float16 s_h0h[2][NH], s_h1h[2][NH];
  __shared__ __align__(16) _Float16 s_embh[NH], s_z[NH], s_xin[NH];
  __shared__ __align__(16) float    s_vb[NH], s_b1[NH], s_b2[NH];
  __shared__ __align__(16) float    s_bc0[1024], s_bc1[1024];
  __shared__ __align__(16) _Float16 s_gw[512];
  __shared__ float s_gate[NS];
  __shared__ int   s_um[NS];
  __shared__ float s_gb;

  if (wid >= 128) {
    // =================== LOGITS WORKER: (b, vocab quarter vq) ===================
    const int widw = wid - 128, b = widw >> 2, vq = widw & 3;
    const int len = lengths[b];
    unsigned* flagRow = flags + ((0 * NB + b) * 4 + 0) * 16;
    const _Float16* feats16 = (const _Float16*)ws + H_FEATS;
    _Float16* s_fe = (_Float16*)s_stkh;             // [32][264] alias
    _Float16* s_h2 = ((_Float16*)s_stkh) + 32 * 264; // [32][264] alias (hidden, t-major)
    const float4 m1 = make_float4(-1.f, -1.f, -1.f, -1.f);

    for (int tile = 0; tile < 16; ++tile) {
      const int t0 = tile * TBR;
      // PAD rows (t >= len) for this vocab quarter
      for (int r = 0; r < TBR; ++r) {
        const int t = t0 + r;
        if (t >= len) {
          float4* row = (float4*)(out + ((size_t)b * NT + t) * NV + vq * 2500);
          for (int i = tid; i < 625; i += 1024) row[i] = m1;
        }
      }
      if (t0 >= len) continue;
      const int te = (t0 + TBR < len) ? t0 + TBR : len;
      // wait for feats[t0..te) to be published+drained (flagD >= te+2; terminal NT+4)
      if (tid == 0) {
        while (__hip_atomic_load(flagRow, __ATOMIC_RELAXED, __HIP_MEMORY_SCOPE_AGENT) < (unsigned)(te + 2))
          __builtin_amdgcn_s_sleep(8);
      }
      __syncthreads();
      // stage feats rows -> LDS (f16); zero pad rows
      for (int idx = tid; idx < 32 * 32; idx += 1024) {
        const int r = idx >> 5, c8 = idx & 31;
        h8 v = {};
        if (t0 + r < te) v = *(const h8*)(feats16 + ((size_t)b * NT + t0 + r) * 256 + c8 * 8);
        *(h8*)(s_fe + r * SPAD + c8 * 8) = v;
      }
      __syncthreads();
      // stage 1: hidden = relu(W1 . feats + b1)  (wave w -> m-tile w)
      {
        const _Float16* aB = hw + P_LW1 + ((size_t)w * 8 * 64 + (size_t)l) * 8;
        h8 af[8];
        #pragma unroll
        for (int kk = 0; kk < 8; ++kk) gload16(af[kk], aB + (size_t)kk * 512);
        VWAIT0(); SBAR();
        #pragma unroll
        for (int nt = 0; nt < 2; ++nt) {
          f32x4 c = {0.f, 0.f, 0.f, 0.f};
          #pragma unroll
          for (int kk = 0; kk < 8; ++kk) {
            const h8 bf = *(const h8*)(s_fe + (nt * 16 + lr) * SPAD + kk * 32 + lk * 8);
            c = __builtin_amdgcn_mfma_f32_16x16x32_f16(af[kk], bf, c, 0, 0, 0);
          }
          #pragma unroll
          for (int i = 0; i < 4; ++i) {
            const int row = w * 16 + lk * 4 + i;
            const float hv = fmaxf(c[i] + outb1[row], 0.f);
            s_h2[(nt * 16 + lr) * SPAD + row] = (_Float16)hv;
          }
        }
      }
      __syncthreads();
      // stage 2: logits = W2 . hidden + b2 ; m-tiles mt ≡ vq (mod 4), wave-strided
      for (int mt = vq + 4 * w; mt < 625; mt += 64) {
        const _Float16* aB = hw + P_LW2 + ((size_t)mt * 8 * 64 + (size_t)l) * 8;
        h8 af[8];
        #pragma unroll
        for (int kk = 0; kk < 8; ++kk) gload16(af[kk], aB + (size_t)kk * 512);
        VWAIT0(); SBAR();
        #pragma unroll
        for (int nt = 0; nt < 2; ++nt) {
          f32x4 c = {0.f, 0.f, 0.f, 0.f};
          #pragma unroll
          for (int kk = 0; kk < 8; ++kk) {
            const h8 bf = *(const h8*)(s_h2 + (nt * 16 + lr) * SPAD + kk * 32 + lk * 8);
            c = __builtin_amdgcn_mfma_f32_16x16x32_f16(af[kk], bf, c, 0, 0, 0);
          }
          const int t = t0 + nt * 16 + lr;
          if (t < te) {
            const int v0 = mt * 16 + lk * 4;
            float4 st = make_float4(c[0] + outb2[v0], c[1] + outb2[v0 + 1],
                                    c[2] + outb2[v0 + 2], c[3] + outb2[v0 + 3]);
            *(float4*)(out + ((size_t)b * NT + t) * NV + v0) = st;
          }
        }
      }
      __syncthreads();   // s_h2/s_fe reuse next tile
    }
    return;
  }

  // =================== SCAN WG (r13-proven structure; quad per row) ===================
  const int b = wid >> 2, q = wid & 3;   // XCD-aligned quad mapping
  const int len = lengths[b];
  float* xb_slot = ws + F_XB;
  unsigned* xd = (unsigned*)(ws + F_XD);
  unsigned* xe = (unsigned*)(ws + F_XE);
  unsigned* flagD = flags + ((0 * NB + b) * 4 + q) * 16;
  unsigned* flagE = flags + ((1 * NB + b) * 4 + q) * 16;
  unsigned* flagB = flags + ((2 * NB + b) * 4 + q) * 16;
  unsigned* featp = (unsigned*)((_Float16*)ws + H_FEATS);

  // ---- one-time init (replicated)
  for (int i = tid; i < 64 * SPAD; i += 1024) ((_Float16*)s_stkh)[i] = (_Float16)0.f;
  for (int i = tid; i < NS * NH; i += 1024) ((float*)s_stk32)[i] = 0.f;
  s_bc0[tid] = ws[F_BC0 + tid];
  s_bc1[tid] = ws[F_BC1 + tid];
  if (tid < NH) {
    s_h0h[0][tid] = (_Float16)h0[b * NH + tid];
    s_h1h[0][tid] = (_Float16)h0[NB * NH + b * NH + tid];
    s_c[0][tid] = c0[b * NH + tid];
    s_c[1][tid] = c0[NB * NH + b * NH + tid];
    s_vb[tid] = valb[tid]; s_b1[tid] = stb1[tid]; s_b2[tid] = stb2[tid];
  }
  if (tid < 64) ((h8*)s_gw)[tid] = ((const h8*)(hw + P_GW))[tid];
  if (tid == 0) s_gb = gateb[0];
  __syncthreads();

  unsigned epB = 0;

  for (int t = 0; t < len; ++t) {
    const int p0 = t & 1, p1 = p0 ^ 1;
    const int tok  = tokens[b * NT + t];
    const int sx   = scope_idx[b * NT + t];
    const int isid = is_id[b * NT + t];
    const unsigned stamp = (unsigned)(t + 1);

    // ---- A: emb -> LDS f16, umask (replicated)
    if (tid < 64) {
      const float4 e = ((const float4*)(emb + (size_t)tok * NE))[tid];
      h4 v = { (_Float16)e.x, (_Float16)e.y, (_Float16)e.z, (_Float16)e.w };
      ((h4*)s_embh)[tid] = v;
    } else if (tid >= 64 && tid < 64 + NS) {
      s_um[tid - 64] = umask[((size_t)b * NT + t) * NS + (tid - 64)];
    }
    __syncthreads();

    if (isid) {
      ++epB;
      // ---- B (M-split): quad owns z rows [q*64,+64); wave w: tile tl=w&3, k-chunk kc=w>>2
      {
        const int tl = w & 3, kc = w >> 2;
        const _Float16* baseB = hw + P_SW1 + ((size_t)((q * 4 + tl) * 16 + kc * 4) * 64 + (size_t)l) * 8;
        h8 A4[4];
        #pragma unroll
        for (int i = 0; i < 4; ++i) gload16(A4[i], baseB + (size_t)i * 512);
        VWAIT0(); SBAR();
        f32x4 c = {0.f, 0.f, 0.f, 0.f};
        #pragma unroll
        for (int i = 0; i < 4; ++i) {
          const int kt = kc * 4 + i;
          const _Float16* xb = (kt < 8) ? &s_stkh[sx][kt * 32]
                                        : (const _Float16*)s_embh + (kt - 8) * 32;
          c = __builtin_amdgcn_mfma_f32_16x16x32_f16(A4[i], *(const h8*)(xb + lk * 8), c, 0, 0, 0);
        }
        if (lr == 0) *((f32x4*)&s_pre[(kc * 4 + tl) * 16 + lk * 4]) = c;
      }
      __syncthreads();
      if (tid < 64) {   // sum k-chunks, relu, publish own z slice
        const int tl2 = tid >> 4, rr = tid & 15;
        const float s = s_pre[tl2 * 16 + rr] + s_pre[(4 + tl2) * 16 + rr]
                      + s_pre[(8 + tl2) * 16 + rr] + s_pre[(12 + tl2) * 16 + rr];
        const float zv = fmaxf(s + s_b1[q * 64 + tid], 0.f);
        __hip_atomic_store((unsigned*)xb_slot + ((size_t)q * NB + b) * 256 + tid,
                           __float_as_uint(zv), __ATOMIC_RELAXED, __HIP_MEMORY_SCOPE_AGENT);
        VWAIT0();
      }
      if (tid == 0)
        __hip_atomic_store(flagB, epB, __ATOMIC_RELAXED, __HIP_MEMORY_SCOPE_AGENT);
      if (tid < 4) {
        unsigned* f = flags + ((2 * NB + b) * 4 + tid) * 16;
        while (__hip_atomic_load(f, __ATOMIC_RELAXED, __HIP_MEMORY_SCOPE_AGENT) < epB)
          __builtin_amdgcn_s_sleep(1);
      }
      __syncthreads();
      if (tid < 256) {
        const unsigned v = __hip_atomic_load((unsigned*)xb_slot + ((size_t)(tid >> 6) * NB + b) * 256 + (tid & 63),
                                             __ATOMIC_RELAXED, __HIP_MEMORY_SCOPE_AGENT);
        s_z[tid] = (_Float16)__uint_as_float(v);
      }
      __syncthreads();
      // ---- C: full (replicated)
      gemv_pipe<8, 1>(hw + P_SW2, w, w, s_z, s_z, s_pre, l);
      __syncthreads();
      if (tid < 256) s_xin[tid] = (_Float16)(s_pre[tid] + s_b2[tid]);
      __syncthreads();
    } else {
      if (tid < 32) ((h8*)s_xin)[tid] = ((const h8*)s_embh)[tid];
      __syncthreads();
    }

    // ---- D (M-split): full-K pre-acts for quad's 256 permuted rows
    gemv_pipe<16, 1>(hw + P_W0, q * 16 + w, w, s_xin, s_h0h[p0], s_pre, l);
    __syncthreads();
    if (tid < 64) {   // owner nonlinearity: cells q*64 + jcl (wave 0)
      const int jcl = tid, cell = q * 64 + jcl;
      const float iv = s_pre[jcl]       + s_bc0[cell];
      const float fv = s_pre[64 + jcl]  + s_bc0[256 + cell];
      const float gv = s_pre[128 + jcl] + s_bc0[512 + cell];
      const float ov = s_pre[192 + jcl] + s_bc0[768 + cell];
      const float c_ = sigm(fv) * s_c[0][cell] + sigm(iv) * tanh_f(gv);
      s_c[0][cell] = c_;
      const float h_ = sigm(ov) * tanh_f(c_);
      __hip_atomic_store(xd + ((size_t)q * NB + b) * 1024 + jcl, __float_as_uint(h_),
                         __ATOMIC_RELAXED, __HIP_MEMORY_SCOPE_AGENT);
      VWAIT0();                       // drains publish + prior feats stores (wave 0)
    }
    if (tid == 0)
      __hip_atomic_store(flagD, stamp, __ATOMIC_RELAXED, __HIP_MEMORY_SCOPE_AGENT);
    if (tid < 4) {
      unsigned* f = flags + ((0 * NB + b) * 4 + tid) * 16;
      while (__hip_atomic_load(f, __ATOMIC_RELAXED, __HIP_MEMORY_SCOPE_AGENT) < stamp)
        __builtin_amdgcn_s_sleep(1);
    }
    __syncthreads();
    if (tid < 256) {   // gather h0
      const unsigned v = __hip_atomic_load(xd + ((size_t)(tid >> 6) * NB + b) * 1024 + (tid & 63),
                                           __ATOMIC_RELAXED, __HIP_MEMORY_SCOPE_AGENT);
      s_h0h[p1][tid] = (_Float16)__uint_as_float(v);
    }
    __syncthreads();

    // ---- E (M-split): same pattern on W1
    gemv_pipe<16, 1>(hw + P_W1, q * 16 + w, w, s_h0h[p1], s_h1h[p0], s_pre, l);
    __syncthreads();
    if (tid < 64) {
      const int jcl = tid, cell = q * 64 + jcl;
      const float iv = s_pre[jcl]       + s_bc1[cell];
      const float fv = s_pre[64 + jcl]  + s_bc1[256 + cell];
      const float gv = s_pre[128 + jcl] + s_bc1[512 + cell];
      const float ov = s_pre[192 + jcl] + s_bc1[768 + cell];
      const float c_ = sigm(fv) * s_c[1][cell] + sigm(iv) * tanh_f(gv);
      s_c[1][cell] = c_;
      const float h_ = sigm(ov) * tanh_f(c_);
      __hip_atomic_store(xe + ((size_t)q * NB + b) * 1024 + jcl, __float_as_uint(h_),
                         __ATOMIC_RELAXED, __HIP_MEMORY_SCOPE_AGENT);
      VWAIT0();
    }
    if (tid == 0)
      __hip_atomic_store(flagE, stamp, __ATOMIC_RELAXED, __HIP_MEMORY_SCOPE_AGENT);
    if (tid < 4) {
      unsigned* f = flags + ((1 * NB + b) * 4 + tid) * 16;
      while (__hip_atomic_load(f, __ATOMIC_RELAXED, __HIP_MEMORY_SCOPE_AGENT) < stamp)
        __builtin_amdgcn_s_sleep(1);
    }
    __syncthreads();
    if (tid < 256) {
      const unsigned v = __hip_atomic_load(xe + ((size_t)(tid >> 6) * NB + b) * 1024 + (tid & 63),
                                           __ATOMIC_RELAXED, __HIP_MEMORY_SCOPE_AGENT);
      const float h_ = __uint_as_float(v);
      s_hf[tid] = h_;
      s_h1h[p1][tid] = (_Float16)h_;
    }
    __syncthreads();
    if (q == 0 && tid < 64) {   // publish feats f16 (wave 0; drained by next D VWAIT0)
      unsigned* fp = featp + ((size_t)b * NT + t) * 128;
      #pragma unroll
      for (int ii = 0; ii < 2; ++ii) {
        const int idx = tid * 2 + ii;
        union { h2 hh; unsigned u; } pk;
        pk.hh[0] = (_Float16)s_hf[idx * 2];
        pk.hh[1] = (_Float16)s_hf[idx * 2 + 1];
        __hip_atomic_store(fp + idx, pk.u, __ATOMIC_RELAXED, __HIP_MEMORY_SCOPE_AGENT);
      }
    }

    // ---- F: vproj (waves 0-7) + slot gates (waves 8-15)  (replicated, r13)
    if (w < 8) {
      gemv_pipe<8, 2>(hw + P_VWO, w * 2, w * 2, s_h1h[p1], s_h1h[p1], s_pre, l);
    } else {
      const int wp = w - 8;
      const h2* gs = (const h2*)s_gw;
      const h2* go = (const h2*)(s_gw + 256);
      const h2* oh = (const h2*)s_h1h[p1];
      float po = dot2f(go[2 * l], oh[2 * l], 0.f);
      po = dot2f(go[2 * l + 1], oh[2 * l + 1], po);
      for (int j = 0; j < 7; ++j) {
        const int s = wp + 8 * j;
        if (s < NS) {
          const h2* sr = (const h2*)s_stkh[s];
          float p = dot2f(gs[2 * l], sr[2 * l], po);
          p = dot2f(gs[2 * l + 1], sr[2 * l + 1], p);
          #pragma unroll
          for (int m = 1; m < 64; m <<= 1) p += __shfl_xor(p, m, 64);
          if (l == 0) s_gate[s] = (s_um[s] > 0) ? -1.f : sigm(p + s_gb);
        }
      }
    }
    __syncthreads();

    // ---- F4: stack GEMM, de-duplicated (proven r13; wave w -> mt=w)
    {
      const int r = w * 16 + lr;
      const _Float16* baseB = hw + P_VWS + ((size_t)(w * 8) * 64 + (size_t)l) * 8;
      h8 bf0[4], bf1[4];
      #pragma unroll
      for (int i = 0; i < 4; ++i) gload16(bf0[i], baseB + (size_t)i * 512);
      #pragma unroll
      for (int i = 0; i < 4; ++i) gload16(bf1[i], baseB + (size_t)(4 + i) * 512);
      const float vpr = s_pre[r] + s_vb[r];
      float nsv[4][4];
      #pragma unroll
      for (int st = 0; st < 4; ++st) {
        h8 af[8];
        #pragma unroll
        for (int kt = 0; kt < 8; ++kt)
          af[kt] = *(const h8*)&s_stkh[st * 16 + lr][kt * 32 + lk * 8];
        if (st == 0) { VWAIT4(); SBAR(); }
        f32x4 c = {0.f, 0.f, 0.f, 0.f};
        #pragma unroll
        for (int kt = 0; kt < 4; ++kt)
          c = __builtin_amdgcn_mfma_f32_16x16x32_f16(af[kt], bf0[kt], c, 0, 0, 0);
        if (st == 0) { VWAIT0(); SBAR(); }
        #pragma unroll
        for (int kt = 4; kt < 8; ++kt)
          c = __builtin_amdgcn_mfma_f32_16x16x32_f16(af[kt], bf1[kt - 4], c, 0, 0, 0);
        #pragma unroll
        for (int i = 0; i < 4; ++i) {
          const int s = st * 16 + lk * 4 + i;
          float ns = 0.f;
          if (s < NS) {
            const float gv = s_gate[s];
            if (gv >= 0.f) ns = s_stk32[s][r] * (1.f - gv) + gv * tanh_f(c[i] + vpr);
          }
          nsv[st][i] = ns;
        }
      }
      __syncthreads();
      #pragma unroll
      for (int st = 0; st < 4; ++st) {
        #pragma unroll
        for (int i = 0; i < 4; ++i) {
          const int s = st * 16 + lk * 4 + i;
          if (s < NS) { s_stk32[s][r] = nsv[st][i]; s_stkh[s][r] = (_Float16)nsv[st][i]; }
        }
      }
    }
    __syncthreads();
  }

  // ---- completion: ensure last feats drained, then terminal stamp for workers
  __syncthreads();
  if (q == 0) {
    if (tid < 64) VWAIT0();
    if (tid == 0)
      __hip_atomic_store(flagD, (unsigned)(NT + 4), __ATOMIC_RELAXED, __HIP_MEMORY_SCOPE_AGENT);
  }
}

extern "C" void kernel_launch(void* const* d_in, const int* in_sizes, int n_in,
                              void* d_out, int out_size, void* d_ws, size_t ws_size,
                              hipStream_t stream) {
  (void)in_sizes; (void)n_in; (void)out_size; (void)ws_size;
  const int* tokens    = (const int*)d_in[0];
  const int* scope_idx = (const int*)d_in[1];
  const int* is_id     = (const int*)d_in[2];
  const int* umask     = (const int*)d_in[3];
  const int* lengths   = (const int*)d_in[4];
  const float* emb   = (const float*)d_in[5];
  const float* wih0  = (const float*)d_in[6];  const float* whh0 = (const float*)d_in[7];
  const float* bih0  = (const float*)d_in[8];  const float* bhh0 = (const float*)d_in[9];
  const float* wih1  = (const float*)d_in[10]; const float* whh1 = (const float*)d_in[11];
  const float* bih1  = (const float*)d_in[12]; const float* bhh1 = (const float*)d_in[13];
  const float* stw1  = (const float*)d_in[14]; const float* stb1 = (const float*)d_in[15];
  const float* stw2  = (const float*)d_in[16]; const float* stb2 = (const float*)d_in[17];
  const float* gatew = (const float*)d_in[18]; const float* gateb = (const float*)d_in[19];
  const float* valw  = (const float*)d_in[20]; const float* valb  = (const float*)d_in[21];
  const float* outw1 = (const float*)d_in[22]; const float* outb1 = (const float*)d_in[23];
  const float* outw2 = (const float*)d_in[24]; const float* outb2 = (const float*)d_in[25];
  const float* h0 = (const float*)d_in[26];
  const float* c0 = (const float*)d_in[27];
  float* ws = (float*)d_ws;
  float* out = (float*)d_out;

  // reset flags [3][32][4][16] (each launch; graph replay includes this)
  (void)hipMemsetAsync(ws + F_CTR, 0, 3 * 32 * 4 * 16 * 4, stream);

  prep_kernel<<<dim3(256), dim3(256), 0, stream>>>(
      wih0, whh0, bih0, bhh0, wih1, whh1, bih1, bhh1, stw1, stw2, valw, gatew,
      outw1, outw2, ws);

  rnn15_kernel<<<dim3(256), dim3(1024), 0, stream>>>(
      tokens, scope_idx, is_id, umask, lengths, emb,
      stb1, stb2, gateb, valb, outb1, outb2, h0, c0, ws, out);
}